// Round 11
// baseline (265.173 us; speedup 1.0000x reference)
//
#include <hip/hip_runtime.h>

// ============================================================================
// ROUND 11: GEMM K-loop restructure. R10: qkv = 75us, MfmaUtil 10.7%, all
// pipes idle; arithmetic says ~2250 cyc/K-iter = HBM latency fully exposed at
// 2 blocks/CU (m97 2-barrier loop drains vmcnt(0) right after issuing loads).
// Fix: BK=64 + double-buffered LDS, ONE barrier/iter, loads prefetched one
// full iteration ahead (AITER-style pipelining at source level). Same for
// o_gemm. prep/attn_split/combine unchanged (clean A/B).
// ============================================================================

typedef __attribute__((ext_vector_type(8))) short short8;
typedef __attribute__((ext_vector_type(4))) short short4v;
typedef __attribute__((ext_vector_type(4))) float f32x4;

#define SCL2E 0.18033688011112042592f /* (1/8) * log2(e) */

__device__ __forceinline__ float bf2f(short s) {
  unsigned u = ((unsigned)(unsigned short)s) << 16;
  return __uint_as_float(u);
}
__device__ __forceinline__ short f2bf(float f) {
  unsigned u = __float_as_uint(f);
  u += 0x7fffu + ((u >> 16) & 1u);
  return (short)(u >> 16);
}
__device__ __forceinline__ void gld_lds16(const void* gp, void* lp) {
  __builtin_amdgcn_global_load_lds(
      (const __attribute__((address_space(1))) unsigned int*)gp,
      (__attribute__((address_space(3))) unsigned int*)lp, 16, 0, 0);
}
__device__ __forceinline__ short4v cvt4(float4 v) {
  short4v o;
  o[0] = f2bf(v.x); o[1] = f2bf(v.y); o[2] = f2bf(v.z); o[3] = f2bf(v.w);
  return o;
}

// ---------------------------------------------------------------------------
// prep (unchanged): mask bit-pack (dtype probe) + fp32->bf16 of W*, x, ctx.
// ---------------------------------------------------------------------------
__global__ __launch_bounds__(256) void prep(
    const unsigned char* __restrict__ mask, unsigned long long* __restrict__ pm,
    const float* __restrict__ Wq, const float* __restrict__ Wkv,
    const float* __restrict__ Wo, const float* __restrict__ x,
    const float* __restrict__ ctx, short* __restrict__ wqb,
    short* __restrict__ wkvb, short* __restrict__ wob,
    short* __restrict__ xb, short* __restrict__ ctxb) {
  const int row = blockIdx.x;
  const int wave = threadIdx.x >> 6, lane = threadIdx.x & 63;
  const unsigned char p8 = mask[lane * 4 + 1];
  const int p32 = ((const int*)mask)[lane * 2 + 1];
  const int shift =
      (__ballot(p8 != 0) != 0ull) ? 0 : ((__ballot(p32 != 0) != 0ull) ? 2 : 3);
  const size_t base = ((size_t)row * 2048) << shift;
#pragma unroll
  for (int j = 0; j < 8; j++) {
    const int c = wave * 512 + j * 64 + lane;
    const unsigned long long bits = __ballot(mask[base + ((size_t)c << shift)] != 0);
    if (lane == 0) pm[(size_t)row * 32 + wave * 8 + j] = bits;
  }
  const int gid = blockIdx.x * 256 + threadIdx.x;  // [0, 524288)
  *(short4v*)(xb + (size_t)gid * 4) = cvt4(((const float4*)x)[gid]);
  *(short4v*)(ctxb + (size_t)gid * 4) = cvt4(((const float4*)ctx)[gid]);
  *(short4v*)(ctxb + (size_t)(gid + 524288) * 4) =
      cvt4(((const float4*)ctx)[gid + 524288]);
  *(short4v*)(wkvb + (size_t)gid * 4) = cvt4(((const float4*)Wkv)[gid]);
  if (gid < 262144) {
    *(short4v*)(wqb + (size_t)gid * 4) = cvt4(((const float4*)Wq)[gid]);
    *(short4v*)(wob + (size_t)gid * 4) = cvt4(((const float4*)Wo)[gid]);
  }
}

// ---------------------------------------------------------------------------
// qkv_gemm v2: 128x128 tile, BK=64, double-buffered LDS, 1 barrier/iter.
// Frag-set f = rs*2+kb (rs = 16-row set 0..7, kb = 32-k block 0..1), 512
// shorts each, staged by one gld_lds16. Wave stages rs {wave, wave+4} x kb.
//  bx < 512 : KV  (A=ctxb, B=wkvb) -> K [b,h,m,d], Vt [b,h,d,m] (+bias)
//  bx >= 512: Q   (A=xb,   B=wqb)  -> Q*SCL2E [b,h,n,d]
// ---------------------------------------------------------------------------
__global__ __launch_bounds__(256, 2)
void qkv_gemm(const short* __restrict__ xb, const short* __restrict__ ctxb,
              const short* __restrict__ wqb, const short* __restrict__ wkvb,
              const float* __restrict__ bias, short* __restrict__ qws,
              short* __restrict__ kws, short* __restrict__ vtws) {
  __shared__ __align__(16) short ldsA[2][16 * 512];  // 32KB
  __shared__ __align__(16) short ldsB[2][16 * 512];  // 32KB
  const int tid = threadIdx.x;
  const int wave = tid >> 6, lane = tid & 63;
  const int l15 = lane & 15, lg = lane >> 4;
  const int bx = blockIdx.x;
  const bool isKV = bx < 512;
  const int rows0 = isKV ? (bx >> 4) * 128 : ((bx - 512) >> 3) * 128;
  const int cols0 = isKV ? (bx & 15) * 128 : ((bx - 512) & 7) * 128;
  const short* Amat = isKV ? ctxb : xb;
  const short* Bw = isKV ? wkvb : wqb;
  const int wr = wave >> 1, wc = wave & 1;

  f32x4 acc[4][4];
#pragma unroll
  for (int i = 0; i < 4; i++)
#pragma unroll
    for (int j = 0; j < 4; j++) acc[i][j] = (f32x4){0.f, 0.f, 0.f, 0.f};

  const short* gaw0 = Amat + (size_t)(rows0 + wave * 16 + l15) * 1024 + lg * 8;
  const short* gaw1 = gaw0 + (size_t)64 * 1024;
  const short* gbw0 = Bw + (size_t)(cols0 + wave * 16 + l15) * 1024 + lg * 8;
  const short* gbw1 = gbw0 + (size_t)64 * 1024;

  auto stage = [&](int buf, int k0) {
    gld_lds16(gaw0 + k0,      &ldsA[buf][(wave * 2 + 0) * 512]);
    gld_lds16(gaw0 + k0 + 32, &ldsA[buf][(wave * 2 + 1) * 512]);
    gld_lds16(gaw1 + k0,      &ldsA[buf][((wave + 4) * 2 + 0) * 512]);
    gld_lds16(gaw1 + k0 + 32, &ldsA[buf][((wave + 4) * 2 + 1) * 512]);
    gld_lds16(gbw0 + k0,      &ldsB[buf][(wave * 2 + 0) * 512]);
    gld_lds16(gbw0 + k0 + 32, &ldsB[buf][(wave * 2 + 1) * 512]);
    gld_lds16(gbw1 + k0,      &ldsB[buf][((wave + 4) * 2 + 0) * 512]);
    gld_lds16(gbw1 + k0 + 32, &ldsB[buf][((wave + 4) * 2 + 1) * 512]);
  };

  stage(0, 0);  // prologue
  for (int it = 0; it < 16; ++it) {
    const int buf = it & 1;
    __syncthreads();  // drains buf's loads (issued a full iter ago) + old reads
    if (it < 15) stage(buf ^ 1, (it + 1) * 64);  // prefetch next chunk
#pragma unroll
    for (int kb = 0; kb < 2; kb++) {
      short8 af[4], bfr[4];
#pragma unroll
      for (int t = 0; t < 4; t++)
        af[t] = *(const short8*)&ldsA[buf][((wr * 4 + t) * 2 + kb) * 512 + lane * 8];
#pragma unroll
      for (int t = 0; t < 4; t++)
        bfr[t] = *(const short8*)&ldsB[buf][((wc * 4 + t) * 2 + kb) * 512 + lane * 8];
#pragma unroll
      for (int i = 0; i < 4; i++)
#pragma unroll
        for (int j = 0; j < 4; j++)
          acc[i][j] =
              __builtin_amdgcn_mfma_f32_16x16x32_bf16(af[i], bfr[j], acc[i][j], 0, 0, 0);
    }
  }

#pragma unroll
  for (int i = 0; i < 4; i++)
#pragma unroll
    for (int j = 0; j < 4; j++)
#pragma unroll
      for (int r = 0; r < 4; r++) {
        const int gr = rows0 + wr * 64 + i * 16 + lg * 4 + r;
        const int gc = cols0 + wc * 64 + j * 16 + l15;
        float v = acc[i][j][r];
        if (isKV) {
          v += bias[gc];
          const int b = gr >> 11, m = gr & 2047;
          const int kv = gc >> 10, hh = (gc >> 6) & 15, d = gc & 63;
          if (kv == 0)
            kws[((((size_t)b * 16 + hh) * 2048 + m) << 6) + d] = f2bf(v);
          else
            vtws[(((size_t)b * 16 + hh) * 64 + d) * 2048 + m] = f2bf(v);
        } else {
          const int b = gr >> 10, n = gr & 1023, hh = gc >> 6, d = gc & 63;
          qws[((((size_t)b * 16 + hh) * 1024 + n) << 6) + d] = f2bf(v * SCL2E);
        }
      }
}

// ---------------------------------------------------------------------------
// attn_split (unchanged): 512 blocks x 512 threads, split-K x2, no-max exp2
// softmax, l via ones-MFMA, bit-packed mask prefetch.
// ---------------------------------------------------------------------------
__global__ __launch_bounds__(512, 2)
void attn_split(const short* __restrict__ Qg, const short* __restrict__ Kg,
                const short* __restrict__ Vtg,
                const unsigned int* __restrict__ pm,
                float* __restrict__ opart, float* __restrict__ lpart) {
  __shared__ __align__(16) short ldsK[8192];
  __shared__ __align__(16) short ldsV[8192];
  __shared__ __align__(16) short ldsP[17408];
  __shared__ __align__(16) short ones[512];
  const int tid = threadIdx.x;
  const int w = tid >> 6, lane = tid & 63;
  const int l15 = lane & 15, lg = lane >> 4;
  const int bx = blockIdx.x;
  const int bhid = bx & 31, qt = (bx >> 5) & 7, half = bx >> 8;
  const int b = bhid >> 4, h = bhid & 15;
  const int n0 = qt * 128, m_base = half * 1024;
  const size_t bh = (size_t)b * 16 + h;
  const short* Qb = Qg + (bh * 1024 + n0) * 64;
  const short* Kb = Kg + (bh << 17);
  const short* Vb = Vtg + (bh << 17);
  const unsigned int* pmw =
      pm + ((size_t)(b * 1024 + n0 + w * 16 + lg * 4) << 6) + (m_base >> 5);

  ones[tid] = 0x3F80;  // bf16 1.0
#pragma unroll
  for (int ii = 0; ii < 2; ii++)
    gld_lds16(Qb + (size_t)(w * 16 + l15) * 64 + ii * 32 + lg * 8,
              &ldsP[(w * 2 + ii) * 512]);
  __syncthreads();
  short8 qf[2];
#pragma unroll
  for (int ks = 0; ks < 2; ks++)
    qf[ks] = *(const short8*)&ldsP[((w * 2 + ks) * 64 + lane) * 8];
  const short8 onesf = *(const short8*)&ones[lane * 8];

  f32x4 o[4], lacc;
#pragma unroll
  for (int ct = 0; ct < 4; ct++) o[ct] = (f32x4){0.f, 0.f, 0.f, 0.f};
  lacc = (f32x4){0.f, 0.f, 0.f, 0.f};
  short* Pme = &ldsP[w * 2176];

  uint4 mk[4], mkn[4];
#pragma unroll
  for (int r = 0; r < 4; r++) mk[r] = *(const uint4*)(pmw + (size_t)r * 64);

  for (int c = 0; c < 8; c++) {
    const int m0 = m_base + c * 128;
    __syncthreads();
#pragma unroll
    for (int ii = 0; ii < 2; ii++) {
      const int f = w * 2 + ii;
      const int t = f >> 1, ks = f & 1;
      gld_lds16(Kb + (size_t)(m0 + t * 16 + l15) * 64 + ks * 32 + lg * 8,
                &ldsK[f * 512]);
      const int ct = f >> 2, ks2 = f & 3;
      gld_lds16(Vb + (size_t)(ct * 16 + l15) * 2048 + (m0 + ks2 * 32 + lg * 8),
                &ldsV[f * 512]);
    }
    if (c < 7) {
#pragma unroll
      for (int r = 0; r < 4; r++)
        mkn[r] = *(const uint4*)(pmw + (size_t)r * 64 + (c + 1) * 4);
    }
    __syncthreads();

    f32x4 s[8];
#pragma unroll
    for (int t = 0; t < 8; t++) s[t] = (f32x4){0.f, 0.f, 0.f, 0.f};
#pragma unroll
    for (int t = 0; t < 8; t++)
#pragma unroll
      for (int ks = 0; ks < 2; ks++) {
        short8 kf = *(const short8*)&ldsK[((t * 2 + ks) * 64 + lane) * 8];
        s[t] = __builtin_amdgcn_mfma_f32_16x16x32_bf16(qf[ks], kf, s[t], 0, 0, 0);
      }

#pragma unroll
    for (int r = 0; r < 4; r++) {
      const unsigned int* mwp = (const unsigned int*)&mk[r];
#pragma unroll
      for (int t = 0; t < 8; t++) {
        const bool att = (mwp[t >> 1] >> (((t & 1) << 4) + l15)) & 1;
        const float p = exp2f(att ? s[t][r] : -1e30f);
        Pme[(lg * 4 + r) * 136 + t * 16 + l15] = f2bf(p);
      }
    }
    short8 pf[4];
#pragma unroll
    for (int ks2 = 0; ks2 < 4; ks2++)
      pf[ks2] = *(const short8*)&Pme[l15 * 136 + ks2 * 32 + lg * 8];
#pragma unroll
    for (int ct = 0; ct < 4; ct++)
#pragma unroll
      for (int ks2 = 0; ks2 < 4; ks2++) {
        short8 vf = *(const short8*)&ldsV[((ct * 4 + ks2) * 64 + lane) * 8];
        o[ct] = __builtin_amdgcn_mfma_f32_16x16x32_bf16(pf[ks2], vf, o[ct], 0, 0, 0);
      }
#pragma unroll
    for (int ks2 = 0; ks2 < 4; ks2++)
      lacc = __builtin_amdgcn_mfma_f32_16x16x32_bf16(pf[ks2], onesf, lacc, 0, 0, 0);
#pragma unroll
    for (int r = 0; r < 4; r++) mk[r] = mkn[r];
  }

#pragma unroll
  for (int ct = 0; ct < 4; ct++)
#pragma unroll
    for (int r = 0; r < 4; r++) {
      const int n = n0 + w * 16 + lg * 4 + r;
      opart[((size_t)half << 21) + (((size_t)b * 1024 + n) << 10) + h * 64 +
            ct * 16 + l15] = o[ct][r];
    }
  if (l15 == 0) {
#pragma unroll
    for (int r = 0; r < 4; r++) {
      const int n = n0 + w * 16 + lg * 4 + r;
      lpart[((size_t)half << 15) + bh * 1024 + n] = lacc[r];
    }
  }
}

// ---------------------------------------------------------------------------
// combine (unchanged): AO_bf16 = (o0 + o1) / (l0 + l1).
// ---------------------------------------------------------------------------
__global__ __launch_bounds__(256) void combine(
    const float* __restrict__ opart, const float* __restrict__ lpart,
    short* __restrict__ ao) {
  const int gid = blockIdx.x * 256 + threadIdx.x;
  const size_t base = (size_t)gid * 4;
  const int row = (int)(base >> 10), col = (int)(base & 1023);
  const int b = row >> 10, n = row & 1023, h = col >> 6;
  const float4 o1 = *(const float4*)(opart + base);
  const float4 o2 = *(const float4*)(opart + (1u << 21) + base);
  const float l1 = lpart[(size_t)(b * 16 + h) * 1024 + n];
  const float l2 = lpart[(1u << 15) + (size_t)(b * 16 + h) * 1024 + n];
  const float inv = 1.f / fmaxf(l1 + l2, 1e-30f);
  short4v o;
  o[0] = f2bf((o1.x + o2.x) * inv); o[1] = f2bf((o1.y + o2.y) * inv);
  o[2] = f2bf((o1.z + o2.z) * inv); o[3] = f2bf((o1.w + o2.w) * inv);
  *(short4v*)(ao + base) = o;
}

// ---------------------------------------------------------------------------
// o_gemm v2: 64x64 tiles, 512 blocks, BK=64, double-buffered, 1 barrier/iter.
// Frag-set f = rs*2+kb; wave stages rs=wave for A and B (2 gld each).
// ---------------------------------------------------------------------------
__global__ __launch_bounds__(256, 2)
void o_gemm(const short* __restrict__ ao, const short* __restrict__ wob,
            float* __restrict__ Of) {
  __shared__ __align__(16) short ldsA[2][8 * 512];  // 16KB
  __shared__ __align__(16) short ldsB[2][8 * 512];  // 16KB
  const int tid = threadIdx.x;
  const int w = tid >> 6, lane = tid & 63;
  const int l15 = lane & 15, lg = lane >> 4;
  const int bx = blockIdx.x;
  const int rows0 = (bx >> 4) * 64, cols0 = (bx & 15) * 64;

  f32x4 acc[4];
#pragma unroll
  for (int j = 0; j < 4; j++) acc[j] = (f32x4){0.f, 0.f, 0.f, 0.f};

  const short* ga = ao + (size_t)(rows0 + w * 16 + l15) * 1024 + lg * 8;
  const short* gb = wob + (size_t)(cols0 + w * 16 + l15) * 1024 + lg * 8;

  auto stage = [&](int buf, int k0) {
    gld_lds16(ga + k0,      &ldsA[buf][(w * 2 + 0) * 512]);
    gld_lds16(ga + k0 + 32, &ldsA[buf][(w * 2 + 1) * 512]);
    gld_lds16(gb + k0,      &ldsB[buf][(w * 2 + 0) * 512]);
    gld_lds16(gb + k0 + 32, &ldsB[buf][(w * 2 + 1) * 512]);
  };

  stage(0, 0);
  for (int it = 0; it < 16; ++it) {
    const int buf = it & 1;
    __syncthreads();
    if (it < 15) stage(buf ^ 1, (it + 1) * 64);
#pragma unroll
    for (int kb = 0; kb < 2; kb++) {
      const short8 af = *(const short8*)&ldsA[buf][(w * 2 + kb) * 512 + lane * 8];
#pragma unroll
      for (int j = 0; j < 4; j++) {
        const short8 bf = *(const short8*)&ldsB[buf][(j * 2 + kb) * 512 + lane * 8];
        acc[j] = __builtin_amdgcn_mfma_f32_16x16x32_bf16(af, bf, acc[j], 0, 0, 0);
      }
    }
  }

#pragma unroll
  for (int j = 0; j < 4; j++)
#pragma unroll
    for (int r = 0; r < 4; r++) {
      const int gr = rows0 + w * 16 + lg * 4 + r;
      const int gc = cols0 + j * 16 + l15;
      Of[(size_t)gr * 1024 + gc] = acc[j][r];
    }
}

extern "C" void kernel_launch(void* const* d_in, const int* in_sizes, int n_in,
                              void* d_out, int out_size, void* d_ws, size_t ws_size,
                              hipStream_t stream) {
  const float* x   = (const float*)d_in[0];   // fp32 (2,1024,1024)
  const float* ctx = (const float*)d_in[1];   // fp32 (2,2048,1024)
  const unsigned char* mask = (const unsigned char*)d_in[2];  // (2,1024,2048)
  const float* Wq  = (const float*)d_in[3];
  const float* Wkv = (const float*)d_in[4];
  const float* bkv = (const float*)d_in[5];
  const float* Wo  = (const float*)d_in[6];
  float* out = (float*)d_out;                 // FP32 (2,1024,1024)

  char* wsb = (char*)d_ws;
  short* qws  = (short*)(wsb);                        // bf16 Q*scl  4MB @0
  short* kws  = (short*)(wsb + (4u << 20));           // bf16 K      8MB @4M
  short* vtws = (short*)(wsb + (12u << 20));          // bf16 V^T    8MB @12M
  short* wqb  = (short*)(wsb + (20u << 20));          // bf16 Wq     2MB @20M
  short* wkvb = (short*)(wsb + (22u << 20));          // bf16 Wkv    4MB @22M
  short* wob  = (short*)(wsb + (26u << 20));          // bf16 Wo     2MB @26M
  unsigned long long* pmws = (unsigned long long*)(wsb + (28u << 20));  // .5MB
  float* opart = (float*)(wsb + (29u << 20));         // fp32 2x8MB  16MB @29M
  float* lpart = (float*)(wsb + (45u << 20));         // fp32 .25MB  @45M
  // xb/ctxb overlap opart (dead until attn_split; xb/ctxb dead after qkv):
  short* xb   = (short*)(wsb + (29u << 20));          // bf16 x      4MB @29M
  short* ctxb = (short*)(wsb + (33u << 20));          // bf16 ctx    8MB @33M
  short* ao = (short*)(wsb + (20u << 20));  // bf16 AO 4MB (reuses wqb/wkvb)

  prep<<<2048, 256, 0, stream>>>(mask, pmws, Wq, Wkv, Wo, x, ctx,
                                 wqb, wkvb, wob, xb, ctxb);
  qkv_gemm<<<640, 256, 0, stream>>>(xb, ctxb, wqb, wkvb, bkv, qws, kws, vtws);
  attn_split<<<512, 512, 0, stream>>>(qws, kws, vtws, (const unsigned int*)pmws,
                                      opart, lpart);
  combine<<<2048, 256, 0, stream>>>(opart, lpart, ao);
  o_gemm<<<512, 256, 0, stream>>>(ao, wob, out);
}

// Round 12
// 231.677 us; speedup vs baseline: 1.1446x; 1.1446x over previous
//
#include <hip/hip_runtime.h>

// ============================================================================
// ROUND 12: (a) REVERT R11 dbuf (reproduced m132: 64KB LDS -> 2-block cap ->
// 1.5 generations -> 99us regression). Back to R10 GEMM structure (16KB LDS).
// (b) NEW: pre-tiled operand layouts. R10's staging gld_lds16 was a 64-lane
// gather at 2KB stride (16 scattered lines/instr); prep/combine now write
// operands in frag-set order so every gld_lds16 reads contiguous 1KB.
// Math/epilogues/attn unchanged -> absmax identical.
// ============================================================================

typedef __attribute__((ext_vector_type(8))) short short8;
typedef __attribute__((ext_vector_type(4))) short short4v;
typedef __attribute__((ext_vector_type(4))) float f32x4;

#define SCL2E 0.18033688011112042592f /* (1/8) * log2(e) */

__device__ __forceinline__ float bf2f(short s) {
  unsigned u = ((unsigned)(unsigned short)s) << 16;
  return __uint_as_float(u);
}
__device__ __forceinline__ short f2bf(float f) {
  unsigned u = __float_as_uint(f);
  u += 0x7fffu + ((u >> 16) & 1u);
  return (short)(u >> 16);
}
__device__ __forceinline__ void gld_lds16(const void* gp, void* lp) {
  __builtin_amdgcn_global_load_lds(
      (const __attribute__((address_space(1))) unsigned int*)gp,
      (__attribute__((address_space(3))) unsigned int*)lp, 16, 0, 0);
}
__device__ __forceinline__ short4v cvt4(float4 v) {
  short4v o;
  o[0] = f2bf(v.x); o[1] = f2bf(v.y); o[2] = f2bf(v.z); o[3] = f2bf(v.w);
  return o;
}
// Tiled layouts: element (row,k) -> frag-set-ordered offset (shorts).
// 128-row tiles (qkv operands): tile rt=row>>7, kc=k>>5, frag f=(row>>4)&7,
// within-frag lane=( (k>>3)&3 )*16 + (row&15), byte j=k&7.
__device__ __forceinline__ size_t off128(int row, int k) {
  return ((size_t)(((row >> 7) * 32 + (k >> 5)) * 8 + ((row >> 4) & 7)) << 9) +
         (((((k >> 3) & 3) * 16 + (row & 15)) << 3) + (k & 7));
}
// 64-row tiles (o_gemm operands): frag f=(row>>4)&3.
__device__ __forceinline__ size_t off64(int row, int k) {
  return ((size_t)(((row >> 6) * 32 + (k >> 5)) * 4 + ((row >> 4) & 3)) << 9) +
         (((((k >> 3) & 3) * 16 + (row & 15)) << 3) + (k & 7));
}

// ---------------------------------------------------------------------------
// prep: (a) mask bit-pack (dtype probe u8/i32/i64); (b) fp32->bf16 TILED
// conversion: xb/ctxb/wqb/wkvb in 128-tile order, wob in 64-tile order.
// grid 2048 x 256; all arrays have K=1024 cols (e>>10=row, e&1023=k).
// ---------------------------------------------------------------------------
__global__ __launch_bounds__(256) void prep(
    const unsigned char* __restrict__ mask, unsigned long long* __restrict__ pm,
    const float* __restrict__ Wq, const float* __restrict__ Wkv,
    const float* __restrict__ Wo, const float* __restrict__ x,
    const float* __restrict__ ctx, short* __restrict__ wqb,
    short* __restrict__ wkvb, short* __restrict__ wob,
    short* __restrict__ xb, short* __restrict__ ctxb) {
  const int row = blockIdx.x;
  const int wave = threadIdx.x >> 6, lane = threadIdx.x & 63;
  const unsigned char p8 = mask[lane * 4 + 1];
  const int p32 = ((const int*)mask)[lane * 2 + 1];
  const int shift =
      (__ballot(p8 != 0) != 0ull) ? 0 : ((__ballot(p32 != 0) != 0ull) ? 2 : 3);
  const size_t mbase = ((size_t)row * 2048) << shift;
#pragma unroll
  for (int j = 0; j < 8; j++) {
    const int c = wave * 512 + j * 64 + lane;
    const unsigned long long bits = __ballot(mask[mbase + ((size_t)c << shift)] != 0);
    if (lane == 0) pm[(size_t)row * 32 + wave * 8 + j] = bits;
  }
  const int gid = blockIdx.x * 256 + threadIdx.x;  // [0, 524288)
  {  // x: 524288 float4
    const int e = gid * 4, r = e >> 10, k = e & 1023;
    *(short4v*)(xb + off128(r, k)) = cvt4(((const float4*)x)[gid]);
  }
  {  // ctx: 1048576 float4 -> 2 per thread
    int e = gid * 4, r = e >> 10, k = e & 1023;
    *(short4v*)(ctxb + off128(r, k)) = cvt4(((const float4*)ctx)[gid]);
    e = (gid + 524288) * 4; r = e >> 10; k = e & 1023;
    *(short4v*)(ctxb + off128(r, k)) = cvt4(((const float4*)ctx)[gid + 524288]);
  }
  {  // Wkv: 524288 float4
    const int e = gid * 4, r = e >> 10, k = e & 1023;
    *(short4v*)(wkvb + off128(r, k)) = cvt4(((const float4*)Wkv)[gid]);
  }
  if (gid < 262144) {  // Wq (128-tile), Wo (64-tile): 1M floats each
    const int e = gid * 4, r = e >> 10, k = e & 1023;
    *(short4v*)(wqb + off128(r, k)) = cvt4(((const float4*)Wq)[gid]);
    *(short4v*)(wob + off64(r, k)) = cvt4(((const float4*)Wo)[gid]);
  }
}

// ---------------------------------------------------------------------------
// qkv_gemm (R10 structure, tiled operands): 128x128 tile, BK=32, 16KB LDS.
// Staging reads are contiguous 1KB per gld_lds16 (frag-set f at tile rt,kc
// lives at ((rt*32+kc)*8+f)*512). 640 blocks:
//  bx < 512 : KV (A=ctxb, B=wkvb) -> K [b,h,m,d], Vt [b,h,d,m] (+bias)
//  bx >= 512: Q  (A=xb,   B=wqb)  -> Q*SCL2E [b,h,n,d]
// ---------------------------------------------------------------------------
__global__ __launch_bounds__(256, 2)
void qkv_gemm(const short* __restrict__ xb, const short* __restrict__ ctxb,
              const short* __restrict__ wqb, const short* __restrict__ wkvb,
              const float* __restrict__ bias, short* __restrict__ qws,
              short* __restrict__ kws, short* __restrict__ vtws) {
  __shared__ __align__(16) short ldsA[8 * 512];
  __shared__ __align__(16) short ldsB[8 * 512];
  const int tid = threadIdx.x;
  const int wave = tid >> 6, lane = tid & 63;
  const int l15 = lane & 15, lg = lane >> 4;
  const int bx = blockIdx.x;
  const bool isKV = bx < 512;
  const int rt = isKV ? (bx >> 4) : ((bx - 512) >> 3);
  const int ct = isKV ? (bx & 15) : ((bx - 512) & 7);
  const short* Amat = isKV ? ctxb : xb;
  const short* Bw = isKV ? wkvb : wqb;
  const int wr = wave >> 1, wc = wave & 1;

  f32x4 acc[4][4];
#pragma unroll
  for (int i = 0; i < 4; i++)
#pragma unroll
    for (int j = 0; j < 4; j++) acc[i][j] = (f32x4){0.f, 0.f, 0.f, 0.f};

  // tiled staging pointers: frag-set f at (rt,kc) = base + kc*4096 + f*512
  const short* ga0 = Amat + (size_t)rt * 131072 + wave * 512 + lane * 8;
  const short* ga1 = ga0 + 2048;  // f = wave+4
  const short* gb0 = Bw + (size_t)ct * 131072 + wave * 512 + lane * 8;
  const short* gb1 = gb0 + 2048;
  short* la0 = &ldsA[wave * 512];
  short* la1 = &ldsA[(wave + 4) * 512];
  short* lb0 = &ldsB[wave * 512];
  short* lb1 = &ldsB[(wave + 4) * 512];

  for (int k0 = 0; k0 < 1024; k0 += 32) {
    const size_t koff = (size_t)(k0 >> 5) * 4096;
    __syncthreads();
    gld_lds16(ga0 + koff, la0);
    gld_lds16(ga1 + koff, la1);
    gld_lds16(gb0 + koff, lb0);
    gld_lds16(gb1 + koff, lb1);
    __syncthreads();
    short8 af[4], bfr[4];
#pragma unroll
    for (int t = 0; t < 4; t++)
      af[t] = *(const short8*)&ldsA[((wr * 4 + t) * 64 + lane) * 8];
#pragma unroll
    for (int t = 0; t < 4; t++)
      bfr[t] = *(const short8*)&ldsB[((wc * 4 + t) * 64 + lane) * 8];
#pragma unroll
    for (int i = 0; i < 4; i++)
#pragma unroll
      for (int j = 0; j < 4; j++)
        acc[i][j] =
            __builtin_amdgcn_mfma_f32_16x16x32_bf16(af[i], bfr[j], acc[i][j], 0, 0, 0);
  }

#pragma unroll
  for (int i = 0; i < 4; i++)
#pragma unroll
    for (int j = 0; j < 4; j++)
#pragma unroll
      for (int r = 0; r < 4; r++) {
        const int gr = rt * 128 + wr * 64 + i * 16 + lg * 4 + r;
        const int gc = ct * 128 + wc * 64 + j * 16 + l15;
        float v = acc[i][j][r];
        if (isKV) {
          v += bias[gc];
          const int b = gr >> 11, m = gr & 2047;
          const int kv = gc >> 10, hh = (gc >> 6) & 15, d = gc & 63;
          if (kv == 0)
            kws[((((size_t)b * 16 + hh) * 2048 + m) << 6) + d] = f2bf(v);
          else
            vtws[(((size_t)b * 16 + hh) * 64 + d) * 2048 + m] = f2bf(v);
        } else {
          const int b = gr >> 10, n = gr & 1023, hh = gc >> 6, d = gc & 63;
          qws[((((size_t)b * 16 + hh) * 1024 + n) << 6) + d] = f2bf(v * SCL2E);
        }
      }
}

// ---------------------------------------------------------------------------
// attn_split (unchanged, R10): 512 blocks x 512 threads, split-K x2, no-max
// exp2 softmax, l via ones-MFMA, bit-packed mask prefetch.
// ---------------------------------------------------------------------------
__global__ __launch_bounds__(512, 2)
void attn_split(const short* __restrict__ Qg, const short* __restrict__ Kg,
                const short* __restrict__ Vtg,
                const unsigned int* __restrict__ pm,
                float* __restrict__ opart, float* __restrict__ lpart) {
  __shared__ __align__(16) short ldsK[8192];
  __shared__ __align__(16) short ldsV[8192];
  __shared__ __align__(16) short ldsP[17408];
  __shared__ __align__(16) short ones[512];
  const int tid = threadIdx.x;
  const int w = tid >> 6, lane = tid & 63;
  const int l15 = lane & 15, lg = lane >> 4;
  const int bx = blockIdx.x;
  const int bhid = bx & 31, qt = (bx >> 5) & 7, half = bx >> 8;
  const int b = bhid >> 4, h = bhid & 15;
  const int n0 = qt * 128, m_base = half * 1024;
  const size_t bh = (size_t)b * 16 + h;
  const short* Qb = Qg + (bh * 1024 + n0) * 64;
  const short* Kb = Kg + (bh << 17);
  const short* Vb = Vtg + (bh << 17);
  const unsigned int* pmw =
      pm + ((size_t)(b * 1024 + n0 + w * 16 + lg * 4) << 6) + (m_base >> 5);

  ones[tid] = 0x3F80;  // bf16 1.0
#pragma unroll
  for (int ii = 0; ii < 2; ii++)
    gld_lds16(Qb + (size_t)(w * 16 + l15) * 64 + ii * 32 + lg * 8,
              &ldsP[(w * 2 + ii) * 512]);
  __syncthreads();
  short8 qf[2];
#pragma unroll
  for (int ks = 0; ks < 2; ks++)
    qf[ks] = *(const short8*)&ldsP[((w * 2 + ks) * 64 + lane) * 8];
  const short8 onesf = *(const short8*)&ones[lane * 8];

  f32x4 o[4], lacc;
#pragma unroll
  for (int ct = 0; ct < 4; ct++) o[ct] = (f32x4){0.f, 0.f, 0.f, 0.f};
  lacc = (f32x4){0.f, 0.f, 0.f, 0.f};
  short* Pme = &ldsP[w * 2176];

  uint4 mk[4], mkn[4];
#pragma unroll
  for (int r = 0; r < 4; r++) mk[r] = *(const uint4*)(pmw + (size_t)r * 64);

  for (int c = 0; c < 8; c++) {
    const int m0 = m_base + c * 128;
    __syncthreads();
#pragma unroll
    for (int ii = 0; ii < 2; ii++) {
      const int f = w * 2 + ii;
      const int t = f >> 1, ks = f & 1;
      gld_lds16(Kb + (size_t)(m0 + t * 16 + l15) * 64 + ks * 32 + lg * 8,
                &ldsK[f * 512]);
      const int ct = f >> 2, ks2 = f & 3;
      gld_lds16(Vb + (size_t)(ct * 16 + l15) * 2048 + (m0 + ks2 * 32 + lg * 8),
                &ldsV[f * 512]);
    }
    if (c < 7) {
#pragma unroll
      for (int r = 0; r < 4; r++)
        mkn[r] = *(const uint4*)(pmw + (size_t)r * 64 + (c + 1) * 4);
    }
    __syncthreads();

    f32x4 s[8];
#pragma unroll
    for (int t = 0; t < 8; t++) s[t] = (f32x4){0.f, 0.f, 0.f, 0.f};
#pragma unroll
    for (int t = 0; t < 8; t++)
#pragma unroll
      for (int ks = 0; ks < 2; ks++) {
        short8 kf = *(const short8*)&ldsK[((t * 2 + ks) * 64 + lane) * 8];
        s[t] = __builtin_amdgcn_mfma_f32_16x16x32_bf16(qf[ks], kf, s[t], 0, 0, 0);
      }

#pragma unroll
    for (int r = 0; r < 4; r++) {
      const unsigned int* mwp = (const unsigned int*)&mk[r];
#pragma unroll
      for (int t = 0; t < 8; t++) {
        const bool att = (mwp[t >> 1] >> (((t & 1) << 4) + l15)) & 1;
        const float p = exp2f(att ? s[t][r] : -1e30f);
        Pme[(lg * 4 + r) * 136 + t * 16 + l15] = f2bf(p);
      }
    }
    short8 pf[4];
#pragma unroll
    for (int ks2 = 0; ks2 < 4; ks2++)
      pf[ks2] = *(const short8*)&Pme[l15 * 136 + ks2 * 32 + lg * 8];
#pragma unroll
    for (int ct = 0; ct < 4; ct++)
#pragma unroll
      for (int ks2 = 0; ks2 < 4; ks2++) {
        short8 vf = *(const short8*)&ldsV[((ct * 4 + ks2) * 64 + lane) * 8];
        o[ct] = __builtin_amdgcn_mfma_f32_16x16x32_bf16(pf[ks2], vf, o[ct], 0, 0, 0);
      }
#pragma unroll
    for (int ks2 = 0; ks2 < 4; ks2++)
      lacc = __builtin_amdgcn_mfma_f32_16x16x32_bf16(pf[ks2], onesf, lacc, 0, 0, 0);
#pragma unroll
    for (int r = 0; r < 4; r++) mk[r] = mkn[r];
  }

#pragma unroll
  for (int ct = 0; ct < 4; ct++)
#pragma unroll
    for (int r = 0; r < 4; r++) {
      const int n = n0 + w * 16 + lg * 4 + r;
      opart[((size_t)half << 21) + (((size_t)b * 1024 + n) << 10) + h * 64 +
            ct * 16 + l15] = o[ct][r];
    }
  if (l15 == 0) {
#pragma unroll
    for (int r = 0; r < 4; r++) {
      const int n = n0 + w * 16 + lg * 4 + r;
      lpart[((size_t)half << 15) + bh * 1024 + n] = lacc[r];
    }
  }
}

// ---------------------------------------------------------------------------
// combine: AO = (o0+o1)/(l0+l1), bf16, written in 64-TILED layout for o_gemm.
// ---------------------------------------------------------------------------
__global__ __launch_bounds__(256) void combine(
    const float* __restrict__ opart, const float* __restrict__ lpart,
    short* __restrict__ aoT) {
  const int gid = blockIdx.x * 256 + threadIdx.x;
  const size_t base = (size_t)gid * 4;
  const int row = (int)(base >> 10), col = (int)(base & 1023);
  const int b = row >> 10, n = row & 1023, h = col >> 6;
  const float4 o1 = *(const float4*)(opart + base);
  const float4 o2 = *(const float4*)(opart + (1u << 21) + base);
  const float l1 = lpart[(size_t)(b * 16 + h) * 1024 + n];
  const float l2 = lpart[(1u << 15) + (size_t)(b * 16 + h) * 1024 + n];
  const float inv = 1.f / fmaxf(l1 + l2, 1e-30f);
  short4v o;
  o[0] = f2bf((o1.x + o2.x) * inv); o[1] = f2bf((o1.y + o2.y) * inv);
  o[2] = f2bf((o1.z + o2.z) * inv); o[3] = f2bf((o1.w + o2.w) * inv);
  *(short4v*)(aoT + off64(row, col)) = o;
}

// ---------------------------------------------------------------------------
// o_gemm (R10 structure, tiled operands): 64x64 tiles, 512 blocks, 8KB LDS.
// Frag-set f at (rt,kc) = base + kc*2048 + f*512 (contiguous 1KB stages).
// ---------------------------------------------------------------------------
__global__ __launch_bounds__(256, 2)
void o_gemm(const short* __restrict__ aoT, const short* __restrict__ wobT,
            float* __restrict__ Of) {
  __shared__ __align__(16) short ldsA[4 * 512];
  __shared__ __align__(16) short ldsB[4 * 512];
  const int tid = threadIdx.x;
  const int w = tid >> 6, lane = tid & 63;
  const int l15 = lane & 15, lg = lane >> 4;
  const int bx = blockIdx.x;
  const int rt = bx >> 4, ct = bx & 15;

  f32x4 acc[4];
#pragma unroll
  for (int j = 0; j < 4; j++) acc[j] = (f32x4){0.f, 0.f, 0.f, 0.f};

  const short* ga = aoT + (size_t)rt * 65536 + w * 512 + lane * 8;
  const short* gb = wobT + (size_t)ct * 65536 + w * 512 + lane * 8;
  short* la = &ldsA[w * 512];
  short* lb = &ldsB[w * 512];

  for (int k0 = 0; k0 < 1024; k0 += 32) {
    const size_t koff = (size_t)(k0 >> 5) * 2048;
    __syncthreads();
    gld_lds16(ga + koff, la);
    gld_lds16(gb + koff, lb);
    __syncthreads();
    const short8 af = *(const short8*)&ldsA[(w * 64 + lane) * 8];
#pragma unroll
    for (int j = 0; j < 4; j++) {
      const short8 bf = *(const short8*)&ldsB[(j * 64 + lane) * 8];
      acc[j] = __builtin_amdgcn_mfma_f32_16x16x32_bf16(af, bf, acc[j], 0, 0, 0);
    }
  }

#pragma unroll
  for (int j = 0; j < 4; j++)
#pragma unroll
    for (int r = 0; r < 4; r++) {
      const int gr = rt * 64 + w * 16 + lg * 4 + r;
      const int gc = ct * 64 + j * 16 + l15;
      Of[(size_t)gr * 1024 + gc] = acc[j][r];
    }
}

extern "C" void kernel_launch(void* const* d_in, const int* in_sizes, int n_in,
                              void* d_out, int out_size, void* d_ws, size_t ws_size,
                              hipStream_t stream) {
  const float* x   = (const float*)d_in[0];   // fp32 (2,1024,1024)
  const float* ctx = (const float*)d_in[1];   // fp32 (2,2048,1024)
  const unsigned char* mask = (const unsigned char*)d_in[2];  // (2,1024,2048)
  const float* Wq  = (const float*)d_in[3];
  const float* Wkv = (const float*)d_in[4];
  const float* bkv = (const float*)d_in[5];
  const float* Wo  = (const float*)d_in[6];
  float* out = (float*)d_out;                 // FP32 (2,1024,1024)

  char* wsb = (char*)d_ws;
  short* qws  = (short*)(wsb);                        // bf16 Q*scl  4MB @0
  short* kws  = (short*)(wsb + (4u << 20));           // bf16 K      8MB @4M
  short* vtws = (short*)(wsb + (12u << 20));          // bf16 V^T    8MB @12M
  short* wqb  = (short*)(wsb + (20u << 20));          // bf16 Wq(T)  2MB @20M
  short* wkvb = (short*)(wsb + (22u << 20));          // bf16 Wkv(T) 4MB @22M
  short* wob  = (short*)(wsb + (26u << 20));          // bf16 Wo(T)  2MB @26M
  unsigned long long* pmws = (unsigned long long*)(wsb + (28u << 20));  // .5MB
  float* opart = (float*)(wsb + (29u << 20));         // fp32 2x8MB  16MB @29M
  float* lpart = (float*)(wsb + (45u << 20));         // fp32 .25MB  @45M
  // xb/ctxb overlap opart (dead until attn_split; xb/ctxb dead after qkv):
  short* xb   = (short*)(wsb + (29u << 20));          // bf16 x(T)   4MB @29M
  short* ctxb = (short*)(wsb + (33u << 20));          // bf16 ctx(T) 8MB @33M
  short* ao = (short*)(wsb + (20u << 20));  // bf16 AO(T) 4MB (reuses wqb/wkvb)

  prep<<<2048, 256, 0, stream>>>(mask, pmws, Wq, Wkv, Wo, x, ctx,
                                 wqb, wkvb, wob, xb, ctxb);
  qkv_gemm<<<640, 256, 0, stream>>>(xb, ctxb, wqb, wkvb, bkv, qws, kws, vtws);
  attn_split<<<512, 512, 0, stream>>>(qws, kws, vtws, (const unsigned int*)pmws,
                                      opart, lpart);
  combine<<<2048, 256, 0, stream>>>(opart, lpart, ao);
  o_gemm<<<512, 256, 0, stream>>>(ao, wob, out);
}